// Round 3
// baseline (16406.839 us; speedup 1.0000x reference)
//
#include <hip/hip_runtime.h>
#include <stdint.h>

#define TT 512
#define BB 256
#define HH 512
#define NOUTC 64

typedef _Float16 f16;
typedef f16 f16x8 __attribute__((ext_vector_type(8)));
typedef f16 f16x4 __attribute__((ext_vector_type(4)));
typedef float f32x4 __attribute__((ext_vector_type(4)));

__device__ __forceinline__ float sigmoidf_(float x) {
  x = fminf(fmaxf(x, -30.f), 30.f);
  return 1.f / (1.f + __expf(-x));
}
__device__ __forceinline__ float tanhf_(float x) {
  x = fminf(fmaxf(x, -15.f), 15.f);
  float e = __expf(2.f * x);
  return (e - 1.f) / (e + 1.f);
}

// Zero d_out (atomicAdd target) and the ws region (barrier counters + h double-buffer).
__global__ void zero_kernel(float* __restrict__ out, int nout4,
                            uint32_t* __restrict__ ws, int nws) {
  int idx = blockIdx.x * blockDim.x + threadIdx.x;
  int stride = gridDim.x * blockDim.x;
  float4 z = {0.f, 0.f, 0.f, 0.f};
  float4* o4 = (float4*)out;
  for (int i = idx; i < nout4; i += stride) o4[i] = z;
  for (int i = idx; i < nws; i += stride) ws[i] = 0u;
}

// Persistent LSTM kernel.
// Grid = 256 blocks (one per CU), block = 256 threads (4 waves).
//   group g = blockIdx & 7  -> batch slice [g*32, g*32+32)   (8 groups)
//   sub   s = blockIdx >> 3 -> hidden slice [s*16, s*16+16)  (32 subs/group)
// Each block owns 64 gate rows (i/f/g/o x 16 hidden) as register-resident f16
// MFMA A-fragments (loaded once). Per step: stage [x_t | h_{t-1}] (f16) in LDS,
// MFMA gates (64x32, K=640), cell update, publish h-slice.
// R2 fix: classifier K-chunks split across the 4 waves (was: all 4 waves
// computed the identical full partial -> out was exactly 4x too large,
// absmax 2.6016 == 3 * ref_max 0.8672).
__global__ __launch_bounds__(256, 1) void lstm_kernel(
    const float* __restrict__ input, const float* __restrict__ dtp,
    const float* __restrict__ W_ih, const float* __restrict__ W_hh,
    const float* __restrict__ b_ih, const float* __restrict__ b_hh,
    const float* __restrict__ W_cls, const float* __restrict__ b_cls,
    float* __restrict__ out, uint32_t* __restrict__ cnt,
    f16* __restrict__ h_buf) {
  __shared__ __align__(16) f16 xh[32][648];        // [batch n][k: 128 x | 512 h], pad 648
  __shared__ __align__(16) float gates_s[64][33];  // [gate*16 + j][n]
  __shared__ __align__(16) f16 h_tile[16][32];     // [j][n]
  __shared__ float bias_s[64];

  const int tid = threadIdx.x;
  const int g = blockIdx.x & 7;
  const int s = blockIdx.x >> 3;
  const int b0 = g * 32;
  const int w = tid >> 6;    // wave id 0..3
  const int lane = tid & 63;
  const int l = lane & 15;
  const int quad = lane >> 4;

  // main-GEMM role: waves 0,1 -> N-tile 0; waves 2,3 -> N-tile 1.
  // waves 0,2 -> gates {i,f}; waves 1,3 -> gates {g,o}.
  const int nt = w >> 1;
  const int mbase = 2 * (w & 1);
  // classifier role: 32 subs = 4 M-tiles x 2 N-tiles x 4 K-quarters;
  // within a block, wave w handles K-chunk it=w of the quarter.
  const int mt_o = s & 3;
  const int nt_o = (s >> 2) & 1;
  const int kq = s >> 3;

  // ---- A-fragments (cat(W_ih, W_hh) rows) -> registers, f16.
  // A[m = lane&15][k = quad*8 + j] per 16x16x32 fragment; 20 K-chunks of 32.
  f16x8 afrag[2][20];
#pragma unroll
  for (int mp = 0; mp < 2; ++mp) {
    const int grow = (mbase + mp) * HH + s * 16 + l;  // global gate row
#pragma unroll
    for (int it = 0; it < 20; ++it) {
      const int kb = it * 32 + quad * 8;
      const float* src = (kb < 128) ? (W_ih + (size_t)grow * 128 + kb)
                                    : (W_hh + (size_t)grow * HH + (kb - 128));
      float4 p0 = *(const float4*)(src);
      float4 p1 = *(const float4*)(src + 4);
      f16x8 a;
      a[0] = (f16)p0.x; a[1] = (f16)p0.y; a[2] = (f16)p0.z; a[3] = (f16)p0.w;
      a[4] = (f16)p1.x; a[5] = (f16)p1.y; a[6] = (f16)p1.z; a[7] = (f16)p1.w;
      afrag[mp][it] = a;
    }
  }
  // ---- W_cls fragment for THIS wave's K-chunk (16 out-rows x 32 K) -> registers
  f16x8 wfrag;
  {
    const int kb = kq * 128 + w * 32 + quad * 8;
    const float* src = W_cls + (size_t)(mt_o * 16 + l) * HH + kb;
    float4 p0 = *(const float4*)(src);
    float4 p1 = *(const float4*)(src + 4);
    wfrag[0] = (f16)p0.x; wfrag[1] = (f16)p0.y;
    wfrag[2] = (f16)p0.z; wfrag[3] = (f16)p0.w;
    wfrag[4] = (f16)p1.x; wfrag[5] = (f16)p1.y;
    wfrag[6] = (f16)p1.z; wfrag[7] = (f16)p1.w;
  }
  float bclsr[4];
#pragma unroll
  for (int r = 0; r < 4; ++r)
    bclsr[r] = (kq == 0 && w == 0) ? b_cls[mt_o * 16 + quad * 4 + r] : 0.f;

  if (tid < 64) {
    const int grow = (tid >> 4) * HH + s * 16 + (tid & 15);
    bias_s[tid] = b_ih[grow] + b_hh[grow];
  }

  float c0 = 0.f, c1 = 0.f;  // cell state: this thread's (j, n) and (j+8, n)

  for (int t = 0; t <= TT; ++t) {
    // ---- wait until all 32 blocks of the group have published h_{t-1}
    if (t > 0 && tid == 0) {
      const uint32_t target = 32u * (uint32_t)t;
      while (__hip_atomic_load(cnt + g * 32, __ATOMIC_ACQUIRE,
                               __HIP_MEMORY_SCOPE_AGENT) < target)
        __builtin_amdgcn_s_sleep(2);
    }
    __syncthreads();

    // ---- stage x_t (f32 -> f16) into xh[:, 0:128]
    if (t < TT) {
#pragma unroll
      for (int ii = 0; ii < 16; ++ii) {
        const int i = ii * 256 + tid;
        const int n = i >> 7, k = i & 127;
        const int row = t * BB + b0 + n;
        float v = (k < 127) ? input[(size_t)row * 127 + k] : dtp[row];
        xh[n][k] = (f16)v;
      }
    }
    // ---- stage h_{t-1} into xh[:, 128:640] via agent-scope 8B atomic loads
    {
      const unsigned long long* hb =
          (const unsigned long long*)(h_buf +
                                      (size_t)((((t + 1) & 1) * 8) + g) *
                                          (32 * HH));
#pragma unroll
      for (int ci = 0; ci < 16; ++ci) {
        const int c = ci * 256 + tid;       // [0, 4096)
        const int n = c >> 7, q = c & 127;  // 128 x 8B chunks per batch row
        unsigned long long v = __hip_atomic_load(
            hb + n * 128 + q, __ATOMIC_RELAXED, __HIP_MEMORY_SCOPE_AGENT);
        *(unsigned long long*)(&xh[n][128 + q * 4]) = v;
      }
    }
    __syncthreads();

    // ---- classifier: out[t-1] = W_cls @ h_{t-1} + b_cls
    // K split: 4 quarters over kq (blocks), 4 chunks over waves (it = w).
    if (t > 0) {
      f32x4 oacc = {0.f, 0.f, 0.f, 0.f};
      const int kc = 128 + kq * 128 + w * 32 + quad * 8;
      f16x8 b = *(const f16x8*)(&xh[nt_o * 16 + l][kc]);
      oacc = __builtin_amdgcn_mfma_f32_16x16x32_f16(wfrag, b, oacc, 0, 0, 0);
      const int brow = b0 + nt_o * 16 + l;
      float* obase =
          out + ((size_t)(t - 1) * BB + brow) * NOUTC + mt_o * 16 + quad * 4;
#pragma unroll
      for (int r = 0; r < 4; ++r) atomicAdd(obase + r, oacc[r] + bclsr[r]);
    }

    if (t < TT) {
      // ---- gates(64x32) = W @ [x_t; h_{t-1}], K = 640
      f32x4 acc0 = {0.f, 0.f, 0.f, 0.f}, acc1 = {0.f, 0.f, 0.f, 0.f};
#pragma unroll
      for (int it = 0; it < 20; ++it) {
        f16x8 b = *(const f16x8*)(&xh[nt * 16 + l][it * 32 + quad * 8]);
        acc0 = __builtin_amdgcn_mfma_f32_16x16x32_f16(afrag[0][it], b, acc0, 0, 0, 0);
        acc1 = __builtin_amdgcn_mfma_f32_16x16x32_f16(afrag[1][it], b, acc1, 0, 0, 0);
      }
      // D layout: col = lane&15 (n), row = quad*4 + reg (hidden-local)
#pragma unroll
      for (int r = 0; r < 4; ++r) {
        gates_s[mbase * 16 + quad * 4 + r][nt * 16 + l] = acc0[r];
        gates_s[(mbase + 1) * 16 + quad * 4 + r][nt * 16 + l] = acc1[r];
      }
      __syncthreads();

      // ---- cell update: thread handles (j, n) and (j+8, n)
      {
        const int j = tid >> 5, n = tid & 31;
        float vi = gates_s[j][n] + bias_s[j];
        float vf = gates_s[16 + j][n] + bias_s[16 + j];
        float vg = gates_s[32 + j][n] + bias_s[32 + j];
        float vo = gates_s[48 + j][n] + bias_s[48 + j];
        float iv = sigmoidf_(vi), fv = sigmoidf_(vf);
        float gv = tanhf_(vg), ov = sigmoidf_(vo);
        c0 = fv * c0 + iv * gv;
        h_tile[j][n] = (f16)(ov * tanhf_(c0));

        const int j1 = j + 8;
        float vi1 = gates_s[j1][n] + bias_s[j1];
        float vf1 = gates_s[16 + j1][n] + bias_s[16 + j1];
        float vg1 = gates_s[32 + j1][n] + bias_s[32 + j1];
        float vo1 = gates_s[48 + j1][n] + bias_s[48 + j1];
        float iv1 = sigmoidf_(vi1), fv1 = sigmoidf_(vf1);
        float gv1 = tanhf_(vg1), ov1 = sigmoidf_(vo1);
        c1 = fv1 * c1 + iv1 * gv1;
        h_tile[j1][n] = (f16)(ov1 * tanhf_(c1));
      }
      __syncthreads();

      // ---- publish h slice via agent-scope 8B atomic stores
      // h_buf[t&1][g][n][s*16 + j], j-contiguous 8B chunks
      f16* hw = h_buf + (size_t)(((t & 1) * 8) + g) * (32 * HH) + s * 16;
      if (tid < 128) {
        const int n = tid >> 2, jc = (tid & 3) * 4;
        union {
          f16x4 h4;
          unsigned long long u;
        } pk;
        pk.h4[0] = h_tile[jc][n];
        pk.h4[1] = h_tile[jc + 1][n];
        pk.h4[2] = h_tile[jc + 2][n];
        pk.h4[3] = h_tile[jc + 3][n];
        __hip_atomic_store((unsigned long long*)(hw + n * HH + jc), pk.u,
                           __ATOMIC_RELAXED, __HIP_MEMORY_SCOPE_AGENT);
      }
      __threadfence();  // drain the stores before the counter bump
      __syncthreads();
      if (tid == 0)
        __hip_atomic_fetch_add(cnt + g * 32, 1u, __ATOMIC_RELEASE,
                               __HIP_MEMORY_SCOPE_AGENT);
    }
  }
}

extern "C" void kernel_launch(void* const* d_in, const int* in_sizes, int n_in,
                              void* d_out, int out_size, void* d_ws,
                              size_t ws_size, hipStream_t stream) {
  const float* input = (const float*)d_in[0];
  const float* dtp = (const float*)d_in[1];
  const float* W_ih = (const float*)d_in[2];
  const float* W_hh = (const float*)d_in[3];
  const float* b_ih = (const float*)d_in[4];
  const float* b_hh = (const float*)d_in[5];
  const float* W_cls = (const float*)d_in[6];
  const float* b_cls = (const float*)d_in[7];
  float* out = (float*)d_out;

  // ws layout: [0,1024): 8 barrier counters (128B apart); [1024, 1024+512K): h double-buffer
  uint32_t* cnt = (uint32_t*)d_ws;
  f16* h_buf = (f16*)((char*)d_ws + 1024);
  const int nws_words = (1024 + 2 * 8 * 32 * HH * 2) / 4;  // 131328

  zero_kernel<<<1024, 256, 0, stream>>>(out, out_size / 4, cnt, nws_words);
  lstm_kernel<<<256, 256, 0, stream>>>(input, dtp, W_ih, W_hh, b_ih, b_hh,
                                       W_cls, b_cls, out, cnt, h_buf);
}

// Round 4
// 14478.825 us; speedup vs baseline: 1.1332x; 1.1332x over previous
//
#include <hip/hip_runtime.h>
#include <stdint.h>

#define TT 512
#define BB 256
#define HH 512
#define NOUTC 64

typedef _Float16 f16;
typedef f16 f16x8 __attribute__((ext_vector_type(8)));
typedef f16 f16x4 __attribute__((ext_vector_type(4)));
typedef float f32x4 __attribute__((ext_vector_type(4)));

__device__ __forceinline__ float sigmoidf_(float x) {
  x = fminf(fmaxf(x, -30.f), 30.f);
  return 1.f / (1.f + __expf(-x));
}
__device__ __forceinline__ float tanhf_(float x) {
  x = fminf(fmaxf(x, -15.f), 15.f);
  float e = __expf(2.f * x);
  return (e - 1.f) / (e + 1.f);
}

// Zero the ws region only (barrier counters + h double-buffer). d_out is now
// written exactly once per element with plain stores -> no zeroing needed.
__global__ void zero_ws(uint32_t* __restrict__ ws, int nws) {
  int idx = blockIdx.x * blockDim.x + threadIdx.x;
  int stride = gridDim.x * blockDim.x;
  for (int i = idx; i < nws; i += stride) ws[i] = 0u;
}

// Persistent LSTM kernel.
// Grid = 256 blocks (one per CU), block = 256 threads (4 waves).
//   group g = blockIdx & 7  -> batch slice [g*32, g*32+32)   (8 groups)
//   sub   s = blockIdx >> 3 -> hidden slice [s*16, s*16+16)  (32 subs/group)
// R3 changes (kill the MALL small-transaction storm, 32us/step -> target ~8):
//  - h_{t-1} staging: plain cached uint4 loads (was 8B agent atomics = 4.3 GB
//    of uncached 8B-granule MALL reads). Coherence via tid0 acquire-spin inv.
//  - classifier: block-local full-K (wave-split + LDS reduce), plain float4
//    stores by blocks s<8 (was 16 scattered atomicAdds per out element =
//    537 MB of 4B RMWs). Off critical path: runs after the counter bump.
//  - x staging hoisted above the barrier spin (overlaps the wait).
__global__ __launch_bounds__(256, 1) void lstm_kernel(
    const float* __restrict__ input, const float* __restrict__ dtp,
    const float* __restrict__ W_ih, const float* __restrict__ W_hh,
    const float* __restrict__ b_ih, const float* __restrict__ b_hh,
    const float* __restrict__ W_cls, const float* __restrict__ b_cls,
    float* __restrict__ out, uint32_t* __restrict__ cnt,
    f16* __restrict__ h_buf) {
  __shared__ __align__(16) f16 xh[32][648];        // [batch n][k: 128 x | 512 h]
  __shared__ __align__(16) float gates_s[64][33];  // [gate*16 + j][n]
  __shared__ __align__(16) f16 h_tile[16][32];     // [j][n]
  __shared__ __align__(16) float red[4][16][17];   // classifier wave partials
  __shared__ float bias_s[64];

  const int tid = threadIdx.x;
  const int g = blockIdx.x & 7;
  const int s = blockIdx.x >> 3;
  const int b0 = g * 32;
  const int w = tid >> 6;    // wave id 0..3
  const int lane = tid & 63;
  const int l = lane & 15;
  const int quad = lane >> 4;

  // main-GEMM role: waves 0,1 -> N-tile 0; waves 2,3 -> N-tile 1.
  // waves 0,2 -> gates {i,f}; waves 1,3 -> gates {g,o}.
  const int nt = w >> 1;
  const int mbase = 2 * (w & 1);
  // classifier role (blocks s<8 only): tile (mt_o, nt_o); K=512 split over waves.
  const int mt_o = s & 3;
  const int nt_o = (s >> 2) & 1;
  const bool cls_block = (s < 8);

  // ---- A-fragments (cat(W_ih, W_hh) rows) -> registers, f16.
  f16x8 afrag[2][20];
#pragma unroll
  for (int mp = 0; mp < 2; ++mp) {
    const int grow = (mbase + mp) * HH + s * 16 + l;  // global gate row
#pragma unroll
    for (int it = 0; it < 20; ++it) {
      const int kb = it * 32 + quad * 8;
      const float* src = (kb < 128) ? (W_ih + (size_t)grow * 128 + kb)
                                    : (W_hh + (size_t)grow * HH + (kb - 128));
      float4 p0 = *(const float4*)(src);
      float4 p1 = *(const float4*)(src + 4);
      f16x8 a;
      a[0] = (f16)p0.x; a[1] = (f16)p0.y; a[2] = (f16)p0.z; a[3] = (f16)p0.w;
      a[4] = (f16)p1.x; a[5] = (f16)p1.y; a[6] = (f16)p1.z; a[7] = (f16)p1.w;
      afrag[mp][it] = a;
    }
  }
  // ---- W_cls fragments: wave w owns K-chunk [w*128, w*128+128) (s<8 only)
  f16x8 wfrag[4];
  if (cls_block) {
#pragma unroll
    for (int it = 0; it < 4; ++it) {
      const int kb = w * 128 + it * 32 + quad * 8;
      const float* src = W_cls + (size_t)(mt_o * 16 + l) * HH + kb;
      float4 p0 = *(const float4*)(src);
      float4 p1 = *(const float4*)(src + 4);
      f16x8 a;
      a[0] = (f16)p0.x; a[1] = (f16)p0.y; a[2] = (f16)p0.z; a[3] = (f16)p0.w;
      a[4] = (f16)p1.x; a[5] = (f16)p1.y; a[6] = (f16)p1.z; a[7] = (f16)p1.w;
      wfrag[it] = a;
    }
  }
  float bcls4[4];
  if (cls_block && tid < 64) {
    const int m4 = (tid & 3) * 4;
#pragma unroll
    for (int r = 0; r < 4; ++r) bcls4[r] = b_cls[mt_o * 16 + m4 + r];
  }

  if (tid < 64) {
    const int grow = (tid >> 4) * HH + s * 16 + (tid & 15);
    bias_s[tid] = b_ih[grow] + b_hh[grow];
  }

  float c0 = 0.f, c1 = 0.f;  // cell state: this thread's (j, n) and (j+8, n)

  for (int t = 0; t <= TT; ++t) {
    // ---- stage x_t (f32 -> f16) into xh[:, 0:128]  (before the spin: overlaps)
    if (t < TT) {
#pragma unroll
      for (int ii = 0; ii < 16; ++ii) {
        const int i = ii * 256 + tid;
        const int n = i >> 7, k = i & 127;
        const int row = t * BB + b0 + n;
        float v = (k < 127) ? input[(size_t)row * 127 + k] : dtp[row];
        xh[n][k] = (f16)v;
      }
    }
    // ---- wait until all 32 blocks of the group have published h_{t-1}
    if (t > 0 && tid == 0) {
      const uint32_t target = 32u * (uint32_t)t;
      while (__hip_atomic_load(cnt + g * 32, __ATOMIC_ACQUIRE,
                               __HIP_MEMORY_SCOPE_AGENT) < target)
        __builtin_amdgcn_s_sleep(2);
    }
    __syncthreads();

    // ---- stage h_{t-1} into xh[:, 128:640], plain cached 16B loads
    {
      const f16* hb = h_buf + (size_t)((((t + 1) & 1) * 8) + g) * (32 * HH);
#pragma unroll
      for (int ci = 0; ci < 8; ++ci) {
        const int c = ci * 256 + tid;           // [0, 2048) 16B-chunks
        const int n = c >> 6, hc = (c & 63) * 8;
        uint4 v = *(const uint4*)(hb + n * HH + hc);
        *(uint4*)(&xh[n][128 + hc]) = v;
      }
    }
    __syncthreads();

    if (t < TT) {
      // ---- gates(64x32) = W @ [x_t; h_{t-1}], K = 640
      f32x4 acc0 = {0.f, 0.f, 0.f, 0.f}, acc1 = {0.f, 0.f, 0.f, 0.f};
#pragma unroll
      for (int it = 0; it < 20; ++it) {
        f16x8 b = *(const f16x8*)(&xh[nt * 16 + l][it * 32 + quad * 8]);
        acc0 = __builtin_amdgcn_mfma_f32_16x16x32_f16(afrag[0][it], b, acc0, 0, 0, 0);
        acc1 = __builtin_amdgcn_mfma_f32_16x16x32_f16(afrag[1][it], b, acc1, 0, 0, 0);
      }
      // D layout: col = lane&15 (n), row = quad*4 + reg (hidden-local)
#pragma unroll
      for (int r = 0; r < 4; ++r) {
        gates_s[mbase * 16 + quad * 4 + r][nt * 16 + l] = acc0[r];
        gates_s[(mbase + 1) * 16 + quad * 4 + r][nt * 16 + l] = acc1[r];
      }
      __syncthreads();

      // ---- cell update: thread handles (j, n) and (j+8, n)
      {
        const int j = tid >> 5, n = tid & 31;
        float vi = gates_s[j][n] + bias_s[j];
        float vf = gates_s[16 + j][n] + bias_s[16 + j];
        float vg = gates_s[32 + j][n] + bias_s[32 + j];
        float vo = gates_s[48 + j][n] + bias_s[48 + j];
        float iv = sigmoidf_(vi), fv = sigmoidf_(vf);
        float gv = tanhf_(vg), ov = sigmoidf_(vo);
        c0 = fv * c0 + iv * gv;
        h_tile[j][n] = (f16)(ov * tanhf_(c0));

        const int j1 = j + 8;
        float vi1 = gates_s[j1][n] + bias_s[j1];
        float vf1 = gates_s[16 + j1][n] + bias_s[16 + j1];
        float vg1 = gates_s[32 + j1][n] + bias_s[32 + j1];
        float vo1 = gates_s[48 + j1][n] + bias_s[48 + j1];
        float iv1 = sigmoidf_(vi1), fv1 = sigmoidf_(vf1);
        float gv1 = tanhf_(vg1), ov1 = sigmoidf_(vo1);
        c1 = fv1 * c1 + iv1 * gv1;
        h_tile[j1][n] = (f16)(ov1 * tanhf_(c1));
      }
      __syncthreads();

      // ---- publish h slice via agent-scope 8B atomic stores (write-through)
      f16* hw = h_buf + (size_t)(((t & 1) * 8) + g) * (32 * HH) + s * 16;
      if (tid < 128) {
        const int n = tid >> 2, jc = (tid & 3) * 4;
        union {
          f16x4 h4;
          unsigned long long u;
        } pk;
        pk.h4[0] = h_tile[jc][n];
        pk.h4[1] = h_tile[jc + 1][n];
        pk.h4[2] = h_tile[jc + 2][n];
        pk.h4[3] = h_tile[jc + 3][n];
        __hip_atomic_store((unsigned long long*)(hw + n * HH + jc), pk.u,
                           __ATOMIC_RELAXED, __HIP_MEMORY_SCOPE_AGENT);
      }
      __threadfence();  // drain stores before the counter bump
      __syncthreads();
      if (tid == 0)
        __hip_atomic_fetch_add(cnt + g * 32, 1u, __ATOMIC_RELEASE,
                               __HIP_MEMORY_SCOPE_AGENT);
    }

    // ---- classifier (off critical path): out[t-1] = W_cls @ h_{t-1} + b_cls
    // Block-local: K=512 split over 4 waves, LDS reduce, plain float4 stores.
    if (t > 0 && cls_block) {
      f32x4 oacc = {0.f, 0.f, 0.f, 0.f};
#pragma unroll
      for (int it = 0; it < 4; ++it) {
        const int kc = 128 + w * 128 + it * 32 + quad * 8;
        f16x8 b = *(const f16x8*)(&xh[nt_o * 16 + l][kc]);
        oacc = __builtin_amdgcn_mfma_f32_16x16x32_f16(wfrag[it], b, oacc, 0, 0, 0);
      }
#pragma unroll
      for (int r = 0; r < 4; ++r) red[w][quad * 4 + r][l] = oacc[r];
      __syncthreads();
      if (tid < 64) {
        const int n = tid >> 2, m4 = (tid & 3) * 4;
        float4 o;
        float* op = (float*)&o;
#pragma unroll
        for (int r = 0; r < 4; ++r)
          op[r] = red[0][m4 + r][n] + red[1][m4 + r][n] + red[2][m4 + r][n] +
                  red[3][m4 + r][n] + bcls4[r];
        float* obase = out + ((size_t)(t - 1) * BB + b0 + nt_o * 16 + n) * NOUTC +
                       mt_o * 16 + m4;
        *(float4*)obase = o;
      }
    }
  }
}

extern "C" void kernel_launch(void* const* d_in, const int* in_sizes, int n_in,
                              void* d_out, int out_size, void* d_ws,
                              size_t ws_size, hipStream_t stream) {
  const float* input = (const float*)d_in[0];
  const float* dtp = (const float*)d_in[1];
  const float* W_ih = (const float*)d_in[2];
  const float* W_hh = (const float*)d_in[3];
  const float* b_ih = (const float*)d_in[4];
  const float* b_hh = (const float*)d_in[5];
  const float* W_cls = (const float*)d_in[6];
  const float* b_cls = (const float*)d_in[7];
  float* out = (float*)d_out;

  // ws layout: [0,1024): 8 barrier counters (128B apart); [1024, 1024+512K): h double-buffer
  uint32_t* cnt = (uint32_t*)d_ws;
  f16* h_buf = (f16*)((char*)d_ws + 1024);
  const int nws_words = (1024 + 2 * 8 * 32 * HH * 2) / 4;  // 131328

  zero_ws<<<256, 256, 0, stream>>>(cnt, nws_words);
  lstm_kernel<<<256, 256, 0, stream>>>(input, dtp, W_ih, W_hh, b_ih, b_hh,
                                       W_cls, b_cls, out, cnt, h_buf);
}

// Round 5
// 5638.592 us; speedup vs baseline: 2.9097x; 2.5678x over previous
//
#include <hip/hip_runtime.h>
#include <stdint.h>

#define TT 512
#define BB 256
#define HH 512
#define NOUTC 64

typedef _Float16 f16;
typedef f16 f16x8 __attribute__((ext_vector_type(8)));
typedef f16 f16x4 __attribute__((ext_vector_type(4)));
typedef float f32x4 __attribute__((ext_vector_type(4)));

__device__ __forceinline__ float sigmoidf_(float x) {
  x = fminf(fmaxf(x, -30.f), 30.f);
  return 1.f / (1.f + __expf(-x));
}
__device__ __forceinline__ float tanhf_(float x) {
  x = fminf(fmaxf(x, -15.f), 15.f);
  float e = __expf(2.f * x);
  return (e - 1.f) / (e + 1.f);
}

// Zero the ws region only (barrier counters + h double-buffer).
__global__ void zero_ws(uint32_t* __restrict__ ws, int nws) {
  int idx = blockIdx.x * blockDim.x + threadIdx.x;
  int stride = gridDim.x * blockDim.x;
  for (int i = idx; i < nws; i += stride) ws[i] = 0u;
}

// Persistent LSTM kernel.
// Grid = 256 blocks (one per CU), block = 256 threads (4 waves).
//   group g = blockIdx & 7  -> batch slice [g*32, g*32+32)   (8 groups)
//   sub   s = blockIdx >> 3 -> hidden slice [s*16, s*16+16)  (32 subs/group)
// R5 theory: R3/R4's stall was cache-maintenance broadcasts (buffer_inv per
// acquire-poll, buffer_wbl2 per threadfence/release) x 64 per XCD per step.
// This version has ZERO cache-maintenance ops in the hot loop:
//  - spin poll: RELAXED agent atomic load (no inv)
//  - publish: agent write-through atomic stores; __syncthreads() drains
//    vmcnt(0) per wave (compiler-guaranteed before s_barrier) -> ordering
//  - counter bump: RELAXED agent fetch_add (no wbl2)
//  - h staging: agent RELAXED 8B atomic loads from MALL (R1-proven correct)
__global__ __launch_bounds__(256, 1) void lstm_kernel(
    const float* __restrict__ input, const float* __restrict__ dtp,
    const float* __restrict__ W_ih, const float* __restrict__ W_hh,
    const float* __restrict__ b_ih, const float* __restrict__ b_hh,
    const float* __restrict__ W_cls, const float* __restrict__ b_cls,
    float* __restrict__ out, uint32_t* __restrict__ cnt,
    f16* __restrict__ h_buf) {
  __shared__ __align__(16) f16 xh[32][648];        // [batch n][k: 128 x | 512 h]
  __shared__ __align__(16) float gates_s[64][33];  // [gate*16 + j][n]
  __shared__ __align__(16) f16 h_tile[16][32];     // [j][n]
  __shared__ __align__(16) float red[4][16][17];   // classifier wave partials
  __shared__ float bias_s[64];

  const int tid = threadIdx.x;
  const int g = blockIdx.x & 7;
  const int s = blockIdx.x >> 3;
  const int b0 = g * 32;
  const int w = tid >> 6;    // wave id 0..3
  const int lane = tid & 63;
  const int l = lane & 15;
  const int quad = lane >> 4;

  // main-GEMM role: waves 0,1 -> N-tile 0; waves 2,3 -> N-tile 1.
  // waves 0,2 -> gates {i,f}; waves 1,3 -> gates {g,o}.
  const int nt = w >> 1;
  const int mbase = 2 * (w & 1);
  // classifier role (blocks s<8 only): tile (mt_o, nt_o); K=512 split over waves.
  const int mt_o = s & 3;
  const int nt_o = (s >> 2) & 1;
  const bool cls_block = (s < 8);

  // ---- A-fragments (cat(W_ih, W_hh) rows) -> registers, f16.
  f16x8 afrag[2][20];
#pragma unroll
  for (int mp = 0; mp < 2; ++mp) {
    const int grow = (mbase + mp) * HH + s * 16 + l;  // global gate row
#pragma unroll
    for (int it = 0; it < 20; ++it) {
      const int kb = it * 32 + quad * 8;
      const float* src = (kb < 128) ? (W_ih + (size_t)grow * 128 + kb)
                                    : (W_hh + (size_t)grow * HH + (kb - 128));
      float4 p0 = *(const float4*)(src);
      float4 p1 = *(const float4*)(src + 4);
      f16x8 a;
      a[0] = (f16)p0.x; a[1] = (f16)p0.y; a[2] = (f16)p0.z; a[3] = (f16)p0.w;
      a[4] = (f16)p1.x; a[5] = (f16)p1.y; a[6] = (f16)p1.z; a[7] = (f16)p1.w;
      afrag[mp][it] = a;
    }
  }
  // ---- W_cls fragments: wave w owns K-chunk [w*128, w*128+128) (s<8 only)
  f16x8 wfrag[4];
  if (cls_block) {
#pragma unroll
    for (int it = 0; it < 4; ++it) {
      const int kb = w * 128 + it * 32 + quad * 8;
      const float* src = W_cls + (size_t)(mt_o * 16 + l) * HH + kb;
      float4 p0 = *(const float4*)(src);
      float4 p1 = *(const float4*)(src + 4);
      f16x8 a;
      a[0] = (f16)p0.x; a[1] = (f16)p0.y; a[2] = (f16)p0.z; a[3] = (f16)p0.w;
      a[4] = (f16)p1.x; a[5] = (f16)p1.y; a[6] = (f16)p1.z; a[7] = (f16)p1.w;
      wfrag[it] = a;
    }
  }
  float bcls4[4];
  if (cls_block && tid < 64) {
    const int m4 = (tid & 3) * 4;
#pragma unroll
    for (int r = 0; r < 4; ++r) bcls4[r] = b_cls[mt_o * 16 + m4 + r];
  }

  if (tid < 64) {
    const int grow = (tid >> 4) * HH + s * 16 + (tid & 15);
    bias_s[tid] = b_ih[grow] + b_hh[grow];
  }

  float c0 = 0.f, c1 = 0.f;  // cell state: this thread's (j, n) and (j+8, n)

  for (int t = 0; t <= TT; ++t) {
    // ---- stage x_t (f32 -> f16) into xh[:, 0:128]  (before the spin: overlaps)
    if (t < TT) {
#pragma unroll
      for (int ii = 0; ii < 16; ++ii) {
        const int i = ii * 256 + tid;
        const int n = i >> 7, k = i & 127;
        const int row = t * BB + b0 + n;
        float v = (k < 127) ? input[(size_t)row * 127 + k] : dtp[row];
        xh[n][k] = (f16)v;
      }
    }
    // ---- wait until all 32 blocks of the group have published h_{t-1}
    // RELAXED poll: no buffer_inv per iteration.
    if (t > 0 && tid == 0) {
      const uint32_t target = 32u * (uint32_t)t;
      while (__hip_atomic_load(cnt + g * 32, __ATOMIC_RELAXED,
                               __HIP_MEMORY_SCOPE_AGENT) < target)
        __builtin_amdgcn_s_sleep(1);
    }
    __syncthreads();

    // ---- stage h_{t-1} into xh[:, 128:640] via agent RELAXED 8B atomic loads
    // (served from the MALL coherence point -> always fresh, no inv needed)
    {
      const unsigned long long* hb =
          (const unsigned long long*)(h_buf +
                                      (size_t)((((t + 1) & 1) * 8) + g) *
                                          (32 * HH));
#pragma unroll
      for (int ci = 0; ci < 16; ++ci) {
        const int c = ci * 256 + tid;       // [0, 4096)
        const int n = c >> 7, q = c & 127;  // 128 x 8B chunks per batch row
        unsigned long long v = __hip_atomic_load(
            hb + n * 128 + q, __ATOMIC_RELAXED, __HIP_MEMORY_SCOPE_AGENT);
        *(unsigned long long*)(&xh[n][128 + q * 4]) = v;
      }
    }
    __syncthreads();

    if (t < TT) {
      // ---- gates(64x32) = W @ [x_t; h_{t-1}], K = 640
      f32x4 acc0 = {0.f, 0.f, 0.f, 0.f}, acc1 = {0.f, 0.f, 0.f, 0.f};
#pragma unroll
      for (int it = 0; it < 20; ++it) {
        f16x8 b = *(const f16x8*)(&xh[nt * 16 + l][it * 32 + quad * 8]);
        acc0 = __builtin_amdgcn_mfma_f32_16x16x32_f16(afrag[0][it], b, acc0, 0, 0, 0);
        acc1 = __builtin_amdgcn_mfma_f32_16x16x32_f16(afrag[1][it], b, acc1, 0, 0, 0);
      }
      // D layout: col = lane&15 (n), row = quad*4 + reg (hidden-local)
#pragma unroll
      for (int r = 0; r < 4; ++r) {
        gates_s[mbase * 16 + quad * 4 + r][nt * 16 + l] = acc0[r];
        gates_s[(mbase + 1) * 16 + quad * 4 + r][nt * 16 + l] = acc1[r];
      }
      __syncthreads();

      // ---- cell update: thread handles (j, n) and (j+8, n)
      {
        const int j = tid >> 5, n = tid & 31;
        float vi = gates_s[j][n] + bias_s[j];
        float vf = gates_s[16 + j][n] + bias_s[16 + j];
        float vg = gates_s[32 + j][n] + bias_s[32 + j];
        float vo = gates_s[48 + j][n] + bias_s[48 + j];
        float iv = sigmoidf_(vi), fv = sigmoidf_(vf);
        float gv = tanhf_(vg), ov = sigmoidf_(vo);
        c0 = fv * c0 + iv * gv;
        h_tile[j][n] = (f16)(ov * tanhf_(c0));

        const int j1 = j + 8;
        float vi1 = gates_s[j1][n] + bias_s[j1];
        float vf1 = gates_s[16 + j1][n] + bias_s[16 + j1];
        float vg1 = gates_s[32 + j1][n] + bias_s[32 + j1];
        float vo1 = gates_s[48 + j1][n] + bias_s[48 + j1];
        float iv1 = sigmoidf_(vi1), fv1 = sigmoidf_(vf1);
        float gv1 = tanhf_(vg1), ov1 = sigmoidf_(vo1);
        c1 = fv1 * c1 + iv1 * gv1;
        h_tile[j1][n] = (f16)(ov1 * tanhf_(c1));
      }
      __syncthreads();

      // ---- publish h slice via agent-scope 8B atomic stores (write-through)
      f16* hw = h_buf + (size_t)(((t & 1) * 8) + g) * (32 * HH) + s * 16;
      if (tid < 128) {
        const int n = tid >> 2, jc = (tid & 3) * 4;
        union {
          f16x4 h4;
          unsigned long long u;
        } pk;
        pk.h4[0] = h_tile[jc][n];
        pk.h4[1] = h_tile[jc + 1][n];
        pk.h4[2] = h_tile[jc + 2][n];
        pk.h4[3] = h_tile[jc + 3][n];
        __hip_atomic_store((unsigned long long*)(hw + n * HH + jc), pk.u,
                           __ATOMIC_RELAXED, __HIP_MEMORY_SCOPE_AGENT);
      }
      // __syncthreads() drains each wave's vmcnt(0) before s_barrier ->
      // all publishes are at the coherence point before tid0's bump.
      __syncthreads();
      if (tid == 0)
        __hip_atomic_fetch_add(cnt + g * 32, 1u, __ATOMIC_RELAXED,
                               __HIP_MEMORY_SCOPE_AGENT);
    }

    // ---- classifier (off critical path): out[t-1] = W_cls @ h_{t-1} + b_cls
    if (t > 0 && cls_block) {
      f32x4 oacc = {0.f, 0.f, 0.f, 0.f};
#pragma unroll
      for (int it = 0; it < 4; ++it) {
        const int kc = 128 + w * 128 + it * 32 + quad * 8;
        f16x8 b = *(const f16x8*)(&xh[nt_o * 16 + l][kc]);
        oacc = __builtin_amdgcn_mfma_f32_16x16x32_f16(wfrag[it], b, oacc, 0, 0, 0);
      }
#pragma unroll
      for (int r = 0; r < 4; ++r) red[w][quad * 4 + r][l] = oacc[r];
      __syncthreads();
      if (tid < 64) {
        const int n = tid >> 2, m4 = (tid & 3) * 4;
        float4 o;
        float* op = (float*)&o;
#pragma unroll
        for (int r = 0; r < 4; ++r)
          op[r] = red[0][m4 + r][n] + red[1][m4 + r][n] + red[2][m4 + r][n] +
                  red[3][m4 + r][n] + bcls4[r];
        float* obase = out + ((size_t)(t - 1) * BB + b0 + nt_o * 16 + n) * NOUTC +
                       mt_o * 16 + m4;
        *(float4*)obase = o;
      }
    }
  }
}

extern "C" void kernel_launch(void* const* d_in, const int* in_sizes, int n_in,
                              void* d_out, int out_size, void* d_ws,
                              size_t ws_size, hipStream_t stream) {
  const float* input = (const float*)d_in[0];
  const float* dtp = (const float*)d_in[1];
  const float* W_ih = (const float*)d_in[2];
  const float* W_hh = (const float*)d_in[3];
  const float* b_ih = (const float*)d_in[4];
  const float* b_hh = (const float*)d_in[5];
  const float* W_cls = (const float*)d_in[6];
  const float* b_cls = (const float*)d_in[7];
  float* out = (float*)d_out;

  // ws layout: [0,1024): 8 barrier counters (128B apart); [1024, 1024+512K): h double-buffer
  uint32_t* cnt = (uint32_t*)d_ws;
  f16* h_buf = (f16*)((char*)d_ws + 1024);
  const int nws_words = (1024 + 2 * 8 * 32 * HH * 2) / 4;  // 131328

  zero_ws<<<256, 256, 0, stream>>>(cnt, nws_words);
  lstm_kernel<<<256, 256, 0, stream>>>(input, dtp, W_ih, W_hh, b_ih, b_hh,
                                       W_cls, b_cls, out, cnt, h_buf);
}

// Round 7
// 3093.414 us; speedup vs baseline: 5.3038x; 1.8228x over previous
//
#include <hip/hip_runtime.h>
#include <stdint.h>

#define TT 512
#define BB 256
#define HH 512
#define NOUTC 64
// 16 groups x 16 blocks; each block: 16 batch x 128 gate rows.
// Group g occupies blocks {g, g+16, ...} -> all on XCD (g&7): MALL-local sync.

typedef _Float16 f16;
typedef f16 f16x8 __attribute__((ext_vector_type(8)));
typedef float f32x4 __attribute__((ext_vector_type(4)));
typedef unsigned long long ull;

__device__ __forceinline__ float sigmoidf_(float x) {
  x = fminf(fmaxf(x, -30.f), 30.f);
  return 1.f / (1.f + __expf(-x));
}
__device__ __forceinline__ float tanhf_(float x) {
  x = fminf(fmaxf(x, -15.f), 15.f);
  float e = __expf(2.f * x);
  return (e - 1.f) / (e + 1.f);
}

// Zero the ws region (flag array + h double-buffer).
__global__ void zero_ws(uint32_t* __restrict__ ws, int nws) {
  int idx = blockIdx.x * blockDim.x + threadIdx.x;
  int stride = gridDim.x * blockDim.x;
  for (int i = idx; i < nws; i += stride) ws[i] = 0u;
}

// Sync design: flags[g][s], one u32 per block on its own 64B line; publisher
// does ONE relaxed agent store; waiter ballot-polls 16 lines in one vmem op.
// R6 fix: h-staging chunk indexing (each h row = 128 x 8B chunks, not 64 —
// the n = c>>6 form wrote xh rows 16..31 OOB, corrupting LDS -> NaN).
__global__ __launch_bounds__(256, 1) void lstm_kernel(
    const float* __restrict__ input, const float* __restrict__ dtp,
    const float* __restrict__ W_ih, const float* __restrict__ W_hh,
    const float* __restrict__ b_ih, const float* __restrict__ b_hh,
    const float* __restrict__ W_cls, const float* __restrict__ b_cls,
    float* __restrict__ out, uint32_t* __restrict__ flg,
    f16* __restrict__ h_buf) {
  __shared__ __align__(16) f16 xh[16][648];         // [n][k: 128 x | 512 h]
  __shared__ __align__(16) float gates_s[128][17];  // [q*32 + hl][n]
  __shared__ __align__(16) f16 h_tile[16][40];      // [n][hl], padded
  __shared__ __align__(16) float red[4][16][17];    // classifier wave partials
  __shared__ float bias_s[128];

  const int tid = threadIdx.x;
  const int g = blockIdx.x & 15;   // group: batch slice [g*16, g*16+16)
  const int s = blockIdx.x >> 4;   // sub: hidden slice [s*32, s*32+32)
  const int b0 = g * 16;
  const int w = tid >> 6;          // wave id 0..3 == gate q (i,f,g,o)
  const int lane = tid & 63;
  const int l = lane & 15;
  const int quad = lane >> 4;

  // classifier role (blocks s<4): out-rows [s*16, s*16+16), K=512 over waves.
  const int mt_o = s & 3;
  const bool cls_block = (s < 4);

  // ---- A-fragments: wave w owns gate w, hidden-local [0,32) = 2 m-tiles.
  // A[m = l][k = quad*8 + j]; 20 K-chunks of 32 (K = 128 x | 512 h).
  f16x8 afrag[2][20];
#pragma unroll
  for (int mp = 0; mp < 2; ++mp) {
    const int grow = w * HH + s * 32 + mp * 16 + l;  // gate row in [0,2048)
#pragma unroll
    for (int it = 0; it < 20; ++it) {
      const int kb = it * 32 + quad * 8;
      const float* src = (kb < 128) ? (W_ih + (size_t)grow * 128 + kb)
                                    : (W_hh + (size_t)grow * HH + (kb - 128));
      float4 p0 = *(const float4*)(src);
      float4 p1 = *(const float4*)(src + 4);
      f16x8 a;
      a[0] = (f16)p0.x; a[1] = (f16)p0.y; a[2] = (f16)p0.z; a[3] = (f16)p0.w;
      a[4] = (f16)p1.x; a[5] = (f16)p1.y; a[6] = (f16)p1.z; a[7] = (f16)p1.w;
      afrag[mp][it] = a;
    }
  }
  // ---- W_cls fragments: wave w owns K-chunk [w*128, (w+1)*128) (s<4 only)
  f16x8 wfrag[4];
  if (cls_block) {
#pragma unroll
    for (int it = 0; it < 4; ++it) {
      const int kb = w * 128 + it * 32 + quad * 8;
      const float* src = W_cls + (size_t)(mt_o * 16 + l) * HH + kb;
      float4 p0 = *(const float4*)(src);
      float4 p1 = *(const float4*)(src + 4);
      f16x8 a;
      a[0] = (f16)p0.x; a[1] = (f16)p0.y; a[2] = (f16)p0.z; a[3] = (f16)p0.w;
      a[4] = (f16)p1.x; a[5] = (f16)p1.y; a[6] = (f16)p1.z; a[7] = (f16)p1.w;
      wfrag[it] = a;
    }
  }
  float bcls4[4] = {0.f, 0.f, 0.f, 0.f};
  if (cls_block && tid < 64) {
    const int m4 = (tid & 3) * 4;
#pragma unroll
    for (int r = 0; r < 4; ++r) bcls4[r] = b_cls[mt_o * 16 + m4 + r];
  }

  if (tid < 128) {  // bias row = q*32 + hl
    const int grow = (tid >> 5) * HH + s * 32 + (tid & 31);
    bias_s[tid] = b_ih[grow] + b_hh[grow];
  }

  // cell state: thread (hl = tid>>4, n = tid&15) and (hl+16, n)
  float c0 = 0.f, c1 = 0.f;

  for (int t = 0; t <= TT; ++t) {
    // ---- stage x_t (f32 -> f16) into xh[:, 0:128] (overlaps the spin)
    if (t < TT) {
#pragma unroll
      for (int ii = 0; ii < 8; ++ii) {
        const int i = ii * 256 + tid;
        const int n = i >> 7, k = i & 127;
        const int row = t * BB + b0 + n;
        float v = (k < 127) ? input[(size_t)row * 127 + k] : dtp[row];
        xh[n][k] = (f16)v;
      }
    }
    // ---- wait for all 16 blocks of the group: ballot-poll 16 flag lines
    if (t > 0 && w == 0) {
      const uint32_t* fp = flg + (size_t)(g * 16 + (lane & 15)) * 16;
      for (;;) {
        uint32_t v = __hip_atomic_load(fp, __ATOMIC_RELAXED,
                                       __HIP_MEMORY_SCOPE_AGENT);
        if (__ballot((lane < 16) ? (v >= (uint32_t)t) : 1) == ~0ull) break;
        __builtin_amdgcn_s_sleep(1);
      }
    }
    __syncthreads();

    // ---- stage h_{t-1} into xh[:, 128:640] via agent RELAXED 8B atomic loads
    // 16 rows x 128 8B-chunks (row = 512 f16 = 1024 B = 128 chunks)
    {
      const ull* hb = (const ull*)(h_buf + (size_t)((((t + 1) & 1) * 16) + g) *
                                               (16 * HH));
#pragma unroll
      for (int ci = 0; ci < 8; ++ci) {
        const int c = ci * 256 + tid;        // [0, 2048)
        const int n = c >> 7, q = c & 127;   // R6 FIX (was >>6 / &63: LDS OOB)
        ull v = __hip_atomic_load(hb + n * 128 + q, __ATOMIC_RELAXED,
                                  __HIP_MEMORY_SCOPE_AGENT);
        *(ull*)(&xh[n][128 + q * 4]) = v;
      }
    }
    __syncthreads();

    if (t < TT) {
      // ---- gates(128x16) = W @ [x_t; h_{t-1}], K = 640
      f32x4 acc0 = {0.f, 0.f, 0.f, 0.f}, acc1 = {0.f, 0.f, 0.f, 0.f};
#pragma unroll
      for (int it = 0; it < 20; ++it) {
        f16x8 b = *(const f16x8*)(&xh[l][it * 32 + quad * 8]);
        acc0 = __builtin_amdgcn_mfma_f32_16x16x32_f16(afrag[0][it], b, acc0, 0, 0, 0);
        acc1 = __builtin_amdgcn_mfma_f32_16x16x32_f16(afrag[1][it], b, acc1, 0, 0, 0);
      }
      // D layout: col = l (n), row = quad*4 + reg (within the 16-row tile)
#pragma unroll
      for (int r = 0; r < 4; ++r) {
        gates_s[w * 32 + quad * 4 + r][l] = acc0[r];
        gates_s[w * 32 + 16 + quad * 4 + r][l] = acc1[r];
      }
      __syncthreads();

      // ---- cell update: thread handles (hl, n) and (hl+16, n)
      {
        const int j = tid >> 4, n = tid & 15;
        float vi = gates_s[j][n] + bias_s[j];
        float vf = gates_s[32 + j][n] + bias_s[32 + j];
        float vg = gates_s[64 + j][n] + bias_s[64 + j];
        float vo = gates_s[96 + j][n] + bias_s[96 + j];
        float iv = sigmoidf_(vi), fv = sigmoidf_(vf);
        float gv = tanhf_(vg), ov = sigmoidf_(vo);
        c0 = fv * c0 + iv * gv;
        h_tile[n][j] = (f16)(ov * tanhf_(c0));

        const int j1 = j + 16;
        float vi1 = gates_s[j1][n] + bias_s[j1];
        float vf1 = gates_s[32 + j1][n] + bias_s[32 + j1];
        float vg1 = gates_s[64 + j1][n] + bias_s[64 + j1];
        float vo1 = gates_s[96 + j1][n] + bias_s[96 + j1];
        float iv1 = sigmoidf_(vi1), fv1 = sigmoidf_(vf1);
        float gv1 = tanhf_(vg1), ov1 = sigmoidf_(vo1);
        c1 = fv1 * c1 + iv1 * gv1;
        h_tile[n][j1] = (f16)(ov1 * tanhf_(c1));
      }
      __syncthreads();

      // ---- publish h slice: 128 threads x one 8B agent atomic store
      // h_buf[t&1][g][n][s*32 + jc..jc+3]
      f16* hw = h_buf + (size_t)(((t & 1) * 16) + g) * (16 * HH) + s * 32;
      if (tid < 128) {
        const int n = tid >> 3, jc = (tid & 7) * 4;
        union {
          f16 h4[4];
          ull u;
        } pk;
        pk.h4[0] = h_tile[n][jc];
        pk.h4[1] = h_tile[n][jc + 1];
        pk.h4[2] = h_tile[n][jc + 2];
        pk.h4[3] = h_tile[n][jc + 3];
        __hip_atomic_store((ull*)(hw + n * HH + jc), pk.u, __ATOMIC_RELAXED,
                           __HIP_MEMORY_SCOPE_AGENT);
      }
      // __syncthreads() drains each wave's vmcnt(0) before s_barrier ->
      // all publishes are at the coherence point before the flag store.
      __syncthreads();
      if (tid == 0)
        __hip_atomic_store(flg + (size_t)(g * 16 + s) * 16, (uint32_t)(t + 1),
                           __ATOMIC_RELAXED, __HIP_MEMORY_SCOPE_AGENT);
    }

    // ---- classifier (off critical path): out[t-1] = W_cls @ h_{t-1} + b_cls
    if (t > 0 && cls_block) {
      f32x4 oacc = {0.f, 0.f, 0.f, 0.f};
#pragma unroll
      for (int it = 0; it < 4; ++it) {
        const int kc = 128 + w * 128 + it * 32 + quad * 8;
        f16x8 b = *(const f16x8*)(&xh[l][kc]);
        oacc = __builtin_amdgcn_mfma_f32_16x16x32_f16(wfrag[it], b, oacc, 0, 0, 0);
      }
#pragma unroll
      for (int r = 0; r < 4; ++r) red[w][quad * 4 + r][l] = oacc[r];
      __syncthreads();
      if (tid < 64) {
        const int n = tid >> 2, m4 = (tid & 3) * 4;
        float4 o;
        float* op = (float*)&o;
#pragma unroll
        for (int r = 0; r < 4; ++r)
          op[r] = red[0][m4 + r][n] + red[1][m4 + r][n] + red[2][m4 + r][n] +
                  red[3][m4 + r][n] + bcls4[r];
        float* obase =
            out + ((size_t)(t - 1) * BB + b0 + n) * NOUTC + mt_o * 16 + m4;
        *(float4*)obase = o;
      }
    }
  }
}

extern "C" void kernel_launch(void* const* d_in, const int* in_sizes, int n_in,
                              void* d_out, int out_size, void* d_ws,
                              size_t ws_size, hipStream_t stream) {
  const float* input = (const float*)d_in[0];
  const float* dtp = (const float*)d_in[1];
  const float* W_ih = (const float*)d_in[2];
  const float* W_hh = (const float*)d_in[3];
  const float* b_ih = (const float*)d_in[4];
  const float* b_hh = (const float*)d_in[5];
  const float* W_cls = (const float*)d_in[6];
  const float* b_cls = (const float*)d_in[7];
  float* out = (float*)d_out;

  // ws layout: [0, 16K): 256 flags, one per 64B line;
  //            [16K, 16K+512K): h double-buffer [2][16][16][512] f16
  uint32_t* flg = (uint32_t*)d_ws;
  f16* h_buf = (f16*)((char*)d_ws + 16384);
  const int nws_words = (16384 + 2 * 16 * 16 * HH * 2) / 4;  // 135168

  zero_ws<<<256, 256, 0, stream>>>(flg, nws_words);
  lstm_kernel<<<256, 256, 0, stream>>>(input, dtp, W_ih, W_hh, b_ih, b_hh,
                                       W_cls, b_cls, out, flg, h_buf);
}